// Round 4
// baseline (119.851 us; speedup 1.0000x reference)
//
#include <hip/hip_runtime.h>
#include <hip/hip_bf16.h>

#define BB 8192
#define DD 256
#define ZN (2 * BB)   // floats to zero: S_all, S_1

typedef float f32x4 __attribute__((ext_vector_type(4)));
typedef __bf16 bf16x8 __attribute__((ext_vector_type(8)));

// sqrt(log2(e)/0.07): fn rows pre-scaled so MFMA acc = sim * log2(e)/T directly
#define FSCALE 4.53981600f

__device__ __forceinline__ void load16_to_lds(const void* g, void* l) {
    __builtin_amdgcn_global_load_lds(
        (const __attribute__((address_space(1))) unsigned int*)g,
        (__attribute__((address_space(3))) unsigned int*)l,
        16, 0, 0);
}

// raw v_exp_f32: args here are |x| <= ~21, no range fixup needed
__device__ __forceinline__ float fast_exp2(float x) {
    float r;
    asm("v_exp_f32 %0, %1" : "=v"(r) : "v"(x));
    return r;
}

// ---------------------------------------------------------------------------
// prep: one wave per row. dist_sq vs center, sigma partials (block-reduced,
// race-free into stats_part[block]), writes the normalized+scaled row in MFMA
// FRAGMENT ORDER. Also zeroes S_all/S_1/out.
// ---------------------------------------------------------------------------
__global__ __launch_bounds__(256) void prep_kernel(
    const float* __restrict__ feat, const int* __restrict__ labels,
    const float* __restrict__ center, __hip_bfloat16* __restrict__ fnf,
    float* __restrict__ dist_sq, float* __restrict__ stats_part,
    float* __restrict__ zacc, float* __restrict__ out)
{
    __shared__ float sh[3][4];
    const int gid = blockIdx.x * 256 + threadIdx.x;
    if (gid < ZN) zacc[gid] = 0.0f;
    if (gid == 0) out[0] = 0.0f;

    const int wave = threadIdx.x >> 6;
    const int lane = threadIdx.x & 63;
    const int row  = blockIdx.x * 4 + wave;

    const float4* frow = reinterpret_cast<const float4*>(feat + (size_t)row * DD);
    const float4* crow = reinterpret_cast<const float4*>(center);
    float4 x = frow[lane];
    float4 c = crow[lane];

    float d0 = x.x - c.x, d1 = x.y - c.y, d2 = x.z - c.z, d3 = x.w - c.w;
    float dsq = d0*d0 + d1*d1 + d2*d2 + d3*d3;
    float nsq = x.x*x.x + x.y*x.y + x.z*x.z + x.w*x.w;
    float sx  = x.x + x.y + x.z + x.w;

    #pragma unroll
    for (int m = 1; m < 64; m <<= 1) {
        dsq += __shfl_xor(dsq, m);
        nsq += __shfl_xor(nsq, m);
        sx  += __shfl_xor(sx,  m);
    }

    float rn = FSCALE / fmaxf(sqrtf(nsq), 1e-12f);

    ushort4 u;
    u.x = __builtin_bit_cast(unsigned short, __float2bfloat16(x.x * rn));
    u.y = __builtin_bit_cast(unsigned short, __float2bfloat16(x.y * rn));
    u.z = __builtin_bit_cast(unsigned short, __float2bfloat16(x.z * rn));
    u.w = __builtin_bit_cast(unsigned short, __float2bfloat16(x.w * rn));

    // lane holds elems e=4*lane..+3: kc=lane/8, quad=(lane%8)/2, half=lane&1
    const int g    = row >> 4;
    const int l15r = row & 15;
    const int kc   = lane >> 3;
    const int qd   = (lane & 7) >> 1;
    const int half = lane & 1;
    const size_t cell = (size_t)((g * 8 + kc) * 64 + qd * 16 + l15r);
    reinterpret_cast<ushort4*>(fnf)[cell * 2 + half] = u;

    if (lane == 0) {
        const float m0 = (labels[row] == 0) ? 1.0f : 0.0f;
        dist_sq[row] = dsq;
        sh[0][wave] = m0;
        sh[1][wave] = sx  * m0;
        sh[2][wave] = nsq * m0;
    }
    __syncthreads();
    if (threadIdx.x == 0) {
        float* sp = stats_part + (size_t)blockIdx.x * 4;
        sp[0] = sh[0][0] + sh[0][1] + sh[0][2] + sh[0][3];
        sp[1] = sh[1][0] + sh[1][1] + sh[1][2] + sh[1][3];
        sp[2] = sh[2][0] + sh[2][1] + sh[2][2] + sh[2][3];
        sp[3] = 0.0f;
    }
}

// ---------------------------------------------------------------------------
// gram v5: fused Gram + masked exp row-sums.
// v4 lesson: occupancy 2x (v3->v4) changed NOTHING -> limiter is the per-tile
// phase critical path (~1400 cyc/tile), dominated by ds_read latency +
// barrier sitting serially before each MFMA cluster (m233 pathology).
// v5: half-tile REGISTER prefetch of B (bvX/bvY, 4x bf16x8 each): each phase
// issues ds_reads for the NEXT half-tile and runs MFMA on regs loaded a half
// tile ago -> MFMA never waits on lgkm; LDS latency hidden under MFMA+exp.
// vmcnt tightens to (2): phase t also reads panel t+1 (stage t+1 landed).
// Epilogue un-deferred (single acc pair). launch_bounds(256,3).
// ---------------------------------------------------------------------------
#define STAGE(T, BUF)                                                          \
  {                                                                            \
    const char* gsrc = (const char*)fnf +                                      \
        (size_t)((colstart + (T) * 16) >> 4) * 8192 + (size_t)tid * 16;        \
    load16_to_lds(gsrc,        &lds[BUF][wave * 1024]);                        \
    load16_to_lds(gsrc + 4096, &lds[BUF][4096 + wave * 1024]);                 \
  }

// wait: own stage loads except NSTR newest retired; barrier makes it
// block-wide; then issue stage(T+3).
#define PHASE(T, NSTR)                                                         \
  {                                                                            \
    asm volatile("s_waitcnt vmcnt(" NSTR ") lgkmcnt(0)" ::: "memory");         \
    __builtin_amdgcn_sched_barrier(0);                                         \
    __builtin_amdgcn_s_barrier();                                              \
    if ((T) + 3 < 32) STAGE((T) + 3, ((T) + 3) & 3);                           \
  }

// load 4 k-chunks of panel PANEL into reg buffer BV
#define DSR(BV, PANEL, KB)                                                     \
  {                                                                            \
    const bf16x8* Bt = reinterpret_cast<const bf16x8*>(lds[(PANEL) & 3]);      \
    _Pragma("unroll")                                                          \
    for (int k = 0; k < 4; ++k) BV[k] = Bt[((KB) + k) * 64 + lane];            \
  }

#define MM(BV, KB)                                                             \
  {                                                                            \
    __builtin_amdgcn_s_setprio(1);                                             \
    _Pragma("unroll")                                                          \
    for (int k = 0; k < 4; ++k) {                                              \
      acc0 = __builtin_amdgcn_mfma_f32_16x16x32_bf16(a[0][(KB) + k], BV[k], acc0, 0, 0, 0); \
      acc1 = __builtin_amdgcn_mfma_f32_16x16x32_bf16(a[1][(KB) + k], BV[k], acc1, 0, 0, 0); \
    }                                                                          \
    __builtin_amdgcn_s_setprio(0);                                             \
  }

#define EPILOGUE(T)                                                            \
  {                                                                            \
    const int colbase = colstart + (T) * 16;                                   \
    const int bcol = colbase + l15;                                            \
    const float w1 = wlab[(T) * 16 + l15];                                     \
    if (colbase + 16 > rowbase && colbase < rowbase + 32) {                    \
      _Pragma("unroll")                                                        \
      for (int r = 0; r < 4; ++r) {                                            \
        const int rr = rowbase + quad * 4 + r;                                 \
        float e0 = (rr == bcol) ? 0.0f : fast_exp2(acc0[r]);                   \
        float e1 = (rr + 16 == bcol) ? 0.0f : fast_exp2(acc1[r]);              \
        sall0[r] += e0; sp10[r] = fmaf(e0, w1, sp10[r]);                       \
        sall1[r] += e1; sp11[r] = fmaf(e1, w1, sp11[r]);                       \
      }                                                                        \
    } else {                                                                   \
      _Pragma("unroll")                                                        \
      for (int r = 0; r < 4; ++r) {                                            \
        float e0 = fast_exp2(acc0[r]);                                         \
        float e1 = fast_exp2(acc1[r]);                                         \
        sall0[r] += e0; sp10[r] = fmaf(e0, w1, sp10[r]);                       \
        sall1[r] += e1; sp11[r] = fmaf(e1, w1, sp11[r]);                       \
      }                                                                        \
    }                                                                          \
  }

// one tile: read own half2, MFMA half1 (regs ready), read next tile half1,
// MFMA half2, epilogue
#define BODY(T, LOADNEXT)                                                      \
  {                                                                            \
    acc0 = (f32x4){0,0,0,0}; acc1 = (f32x4){0,0,0,0};                          \
    DSR(bvY, (T), 4);                                                          \
    MM(bvX, 0);                                                                \
    if (LOADNEXT) DSR(bvX, (T) + 1, 0);                                        \
    MM(bvY, 4);                                                                \
    EPILOGUE(T);                                                               \
  }

__global__ __launch_bounds__(256, 3) void gram_kernel(
    const __hip_bfloat16* __restrict__ fnf, const int* __restrict__ labels,
    float* __restrict__ S_all, float* __restrict__ S_1)
{
    __shared__ __align__(16) char lds[4][8192];
    __shared__ float wlab[512];

    const int tid  = threadIdx.x;
    const int lane = tid & 63;
    const int wave = tid >> 6;
    const int l15  = lane & 15;
    const int quad = lane >> 4;

    const int cs = blockIdx.x & 15;       // col split  (16 splits x 512 cols)
    const int rb = blockIdx.x >> 4;       // row block  (64 blocks x 128 rows)
    const int rowbase  = rb * 128 + wave * 32;
    const int colstart = cs * 512;

    const bf16x8* __restrict__ F = reinterpret_cast<const bf16x8*>(fnf);

    // A fragments: 2 sub-tiles x 8 k-chunks = 32 rows/wave, coalesced loads
    bf16x8 a[2][8];
    #pragma unroll
    for (int s = 0; s < 2; ++s)
        #pragma unroll
        for (int kc = 0; kc < 8; ++kc)
            a[s][kc] = F[(size_t)((((rowbase >> 4) + s) * 8 + kc)) * 64 + lane];

    f32x4 sall0 = {0,0,0,0}, sall1 = {0,0,0,0};
    f32x4 sp10  = {0,0,0,0}, sp11  = {0,0,0,0};
    f32x4 acc0, acc1;
    bf16x8 bvX[4], bvY[4];

    // prologue: 3 stages in flight, label weights to LDS
    STAGE(0, 0);
    STAGE(1, 1);
    STAGE(2, 2);
    #pragma unroll
    for (int i = tid; i < 512; i += 256) wlab[i] = (float)labels[colstart + i];

    // first phase: panels 0,1 landed block-wide; issue stage 3; preload half1
    asm volatile("s_waitcnt vmcnt(2) lgkmcnt(0)" ::: "memory");
    __builtin_amdgcn_sched_barrier(0);
    __builtin_amdgcn_s_barrier();
    STAGE(3, 3);
    DSR(bvX, 0, 0);

    BODY(0, 1);

    int t = 1;
    #pragma unroll 1
    for (int it = 0; it < 29; ++it) {
        PHASE(t, "2");        // stages t,t+1 landed; t+2 may fly
        BODY(t, 1);
        ++t;
    }
    // t == 30: need panel 31 readable in body -> drain
    PHASE(30, "0");
    BODY(30, 1);
    PHASE(31, "0");
    BODY(31, 0);

    // reduce over the 16 cols held across low lane bits, one atomic/row/block
    #pragma unroll
    for (int r = 0; r < 4; ++r) {
        float va0 = sall0[r], v10 = sp10[r];
        float va1 = sall1[r], v11 = sp11[r];
        #pragma unroll
        for (int m = 1; m < 16; m <<= 1) {
            va0 += __shfl_xor(va0, m);
            v10 += __shfl_xor(v10, m);
            va1 += __shfl_xor(va1, m);
            v11 += __shfl_xor(v11, m);
        }
        if (l15 == 0) {
            const int grow = rowbase + quad * 4 + r;
            atomicAdd(&S_all[grow],      va0);
            atomicAdd(&S_1[grow],        v10);
            atomicAdd(&S_all[grow + 16], va1);
            atomicAdd(&S_1[grow + 16],   v11);
        }
    }
}

// ---------------------------------------------------------------------------
// finalize: fold 2048 sigma partials (redundantly per block, coalesced
// float4), then per-row losses + mean reduction into out[0].
// ---------------------------------------------------------------------------
__global__ __launch_bounds__(256) void finalize_kernel(
    const int* __restrict__ labels, const float* __restrict__ dist_sq,
    const float* __restrict__ S_all, const float* __restrict__ S_1,
    const float* __restrict__ stats_part, const float* __restrict__ rsigma,
    float* __restrict__ out)
{
    __shared__ float sh[3][4];
    const int lane = threadIdx.x & 63;
    const int wave = threadIdx.x >> 6;

    float c = 0.0f, s = 0.0f, q = 0.0f;
    const float4* sp = reinterpret_cast<const float4*>(stats_part);
    #pragma unroll
    for (int b = 0; b < 8; ++b) {
        const float4 v = sp[b * 256 + threadIdx.x];
        c += v.x; s += v.y; q += v.z;
    }
    #pragma unroll
    for (int m = 1; m < 64; m <<= 1) {
        c += __shfl_xor(c, m);
        s += __shfl_xor(s, m);
        q += __shfl_xor(q, m);
    }
    if (lane == 0) { sh[0][wave] = c; sh[1][wave] = s; sh[2][wave] = q; }
    __syncthreads();

    const float n0   = sh[0][0] + sh[0][1] + sh[0][2] + sh[0][3];
    const float ssx  = sh[1][0] + sh[1][1] + sh[1][2] + sh[1][3];
    const float snsq = sh[2][0] + sh[2][1] + sh[2][2] + sh[2][3];

    const float n_el = n0 * (float)DD;
    const float mean = ssx / n_el;
    const float var  = (snsq - n_el * mean * mean) / (n_el - 1.0f);
    const float sigma_new  = 0.9f * rsigma[0] + 0.1f * sqrtf(var);
    const float m_adaptive = 0.5f + 0.3f * sigma_new + 0.3f * (1.0f - 224.0f / 900.0f);

    const int i = blockIdx.x * 256 + threadIdx.x;
    const int l = labels[i];
    const float dsq = dist_sq[i];

    const float r_center = (l == 0) ? dsq : 0.0f;
    const float r_margin = (l == 1) ? fmaxf(m_adaptive - sqrtf(dsq), 0.0f) : 0.0f;

    const float sallv = S_all[i];
    const float s1v   = S_1[i];
    const float s0v   = sallv - s1v;
    const float pos = (l == 0) ? s0v : s1v;
    const float neg = (l == 0) ? s1v : s0v;

    const float n1 = (float)BB - n0;
    const float cnt_same = ((l == 0) ? n0 : n1) - 1.0f;
    const float cnt_diff = (l == 0) ? n1 : n0;

    float r_con = 0.0f;
    if (cnt_same > 0.0f && cnt_diff > 0.0f)
        r_con = logf(pos + neg + 1e-8f) - logf(pos);

    float tot = (r_center + r_margin + 0.5f * r_con) * (1.0f / (float)BB);

    #pragma unroll
    for (int m = 1; m < 64; m <<= 1) tot += __shfl_xor(tot, m);
    if ((threadIdx.x & 63) == 0) atomicAdd(out, tot);
}

// ---------------------------------------------------------------------------
// launch
// ---------------------------------------------------------------------------
extern "C" void kernel_launch(void* const* d_in, const int* in_sizes, int n_in,
                              void* d_out, int out_size, void* d_ws, size_t ws_size,
                              hipStream_t stream) {
    const float* feat   = (const float*)d_in[0];
    const int*   labels = (const int*)d_in[1];
    const float* center = (const float*)d_in[2];
    const float* rsigma = (const float*)d_in[3];
    float* out = (float*)d_out;

    char* ws = (char*)d_ws;
    __hip_bfloat16* fnf = (__hip_bfloat16*)ws;                    // B*D bf16 = 4 MB, fragment order
    float* dist_sq   = (float*)(ws + (size_t)BB * DD * 2);        // B floats
    float* S_all     = dist_sq + BB;                              // B floats
    float* S_1       = S_all + BB;                                // B floats
    float* stats_part= S_1 + BB;                                  // 2048*4 floats

    prep_kernel<<<dim3(BB / 4), dim3(256), 0, stream>>>(feat, labels, center, fnf,
                                                        dist_sq, stats_part, S_all, out);
    gram_kernel<<<dim3(64 * 16), dim3(256), 0, stream>>>(fnf, labels, S_all, S_1);
    finalize_kernel<<<dim3(BB / 256), dim3(256), 0, stream>>>(labels, dist_sq, S_all, S_1,
                                                              stats_part, rsigma, out);
}

// Round 5
// 109.602 us; speedup vs baseline: 1.0935x; 1.0935x over previous
//
#include <hip/hip_runtime.h>
#include <hip/hip_bf16.h>

#define BB 8192
#define DD 256
#define ZN (2 * BB)   // floats to zero: S_all, S_1

typedef float f32x4 __attribute__((ext_vector_type(4)));
typedef __bf16 bf16x8 __attribute__((ext_vector_type(8)));

// sqrt(log2(e)/0.07): fn rows pre-scaled so MFMA acc = sim * log2(e)/T directly
#define FSCALE 4.53981600f

__device__ __forceinline__ void load16_to_lds(const void* g, void* l) {
    __builtin_amdgcn_global_load_lds(
        (const __attribute__((address_space(1))) unsigned int*)g,
        (__attribute__((address_space(3))) unsigned int*)l,
        16, 0, 0);
}

// raw v_exp_f32: args here are |x| <= ~21, no range fixup needed
__device__ __forceinline__ float fast_exp2(float x) {
    float r;
    asm("v_exp_f32 %0, %1" : "=v"(r) : "v"(x));
    return r;
}

// ---------------------------------------------------------------------------
// prep: one wave per row. dist_sq vs center, sigma partials (block-reduced,
// race-free into stats_part[block]), writes the normalized+scaled row in MFMA
// FRAGMENT ORDER. Also zeroes S_all/S_1/out.
// ---------------------------------------------------------------------------
__global__ __launch_bounds__(256) void prep_kernel(
    const float* __restrict__ feat, const int* __restrict__ labels,
    const float* __restrict__ center, __hip_bfloat16* __restrict__ fnf,
    float* __restrict__ dist_sq, float* __restrict__ stats_part,
    float* __restrict__ zacc, float* __restrict__ out)
{
    __shared__ float sh[3][4];
    const int gid = blockIdx.x * 256 + threadIdx.x;
    if (gid < ZN) zacc[gid] = 0.0f;
    if (gid == 0) out[0] = 0.0f;

    const int wave = threadIdx.x >> 6;
    const int lane = threadIdx.x & 63;
    const int row  = blockIdx.x * 4 + wave;

    const float4* frow = reinterpret_cast<const float4*>(feat + (size_t)row * DD);
    const float4* crow = reinterpret_cast<const float4*>(center);
    float4 x = frow[lane];
    float4 c = crow[lane];

    float d0 = x.x - c.x, d1 = x.y - c.y, d2 = x.z - c.z, d3 = x.w - c.w;
    float dsq = d0*d0 + d1*d1 + d2*d2 + d3*d3;
    float nsq = x.x*x.x + x.y*x.y + x.z*x.z + x.w*x.w;
    float sx  = x.x + x.y + x.z + x.w;

    #pragma unroll
    for (int m = 1; m < 64; m <<= 1) {
        dsq += __shfl_xor(dsq, m);
        nsq += __shfl_xor(nsq, m);
        sx  += __shfl_xor(sx,  m);
    }

    float rn = FSCALE / fmaxf(sqrtf(nsq), 1e-12f);

    ushort4 u;
    u.x = __builtin_bit_cast(unsigned short, __float2bfloat16(x.x * rn));
    u.y = __builtin_bit_cast(unsigned short, __float2bfloat16(x.y * rn));
    u.z = __builtin_bit_cast(unsigned short, __float2bfloat16(x.z * rn));
    u.w = __builtin_bit_cast(unsigned short, __float2bfloat16(x.w * rn));

    // lane holds elems e=4*lane..+3: kc=lane/8, quad=(lane%8)/2, half=lane&1
    const int g    = row >> 4;
    const int l15r = row & 15;
    const int kc   = lane >> 3;
    const int qd   = (lane & 7) >> 1;
    const int half = lane & 1;
    const size_t cell = (size_t)((g * 8 + kc) * 64 + qd * 16 + l15r);
    reinterpret_cast<ushort4*>(fnf)[cell * 2 + half] = u;

    if (lane == 0) {
        const float m0 = (labels[row] == 0) ? 1.0f : 0.0f;
        dist_sq[row] = dsq;
        sh[0][wave] = m0;
        sh[1][wave] = sx  * m0;
        sh[2][wave] = nsq * m0;
    }
    __syncthreads();
    if (threadIdx.x == 0) {
        float* sp = stats_part + (size_t)blockIdx.x * 4;
        sp[0] = sh[0][0] + sh[0][1] + sh[0][2] + sh[0][3];
        sp[1] = sh[1][0] + sh[1][1] + sh[1][2] + sh[1][3];
        sp[2] = sh[2][0] + sh[2][1] + sh[2][2] + sh[2][3];
        sp[3] = 0.0f;
    }
}

// ---------------------------------------------------------------------------
// gram v6: fused Gram + masked exp row-sums.
// Evidence: v3 (64r/wave, 2blk/CU) == v4 (32r/wave, 4blk/CU) == ~45us with
// ~3370 cyc/phase vs ~800 cyc of pipe work -> per-phase OVERHEAD dominates
// (barrier convoy + vmcnt edge + ds_read latency). v5's mid-body reg
// prefetch regressed (compiler pipelining defeated) -> reverted.
// v6 single change vs v4: panel 16 -> 32 cols, 16 phases instead of 32.
// Per-phase: 16 ds_read_b128, 32 MFMA/wave (4 indep chains), 16 exp.
// LDS 4 x 16KB + wlab = 66KB, launch_bounds(256,2) (occupancy >2blk/CU
// proven worthless in R3). vmcnt: 4 loads/stage, depth 3 -> steady "8".
// ---------------------------------------------------------------------------
#define STAGE(T, BUF)                                                          \
  {                                                                            \
    const char* gsrc = (const char*)fnf +                                      \
        (size_t)((colstart + (T) * 32) >> 4) * 8192 + (size_t)tid * 16;        \
    load16_to_lds(gsrc,         &lds[BUF][wave * 1024]);                       \
    load16_to_lds(gsrc + 4096,  &lds[BUF][4096 + wave * 1024]);                \
    load16_to_lds(gsrc + 8192,  &lds[BUF][8192 + wave * 1024]);                \
    load16_to_lds(gsrc + 12288, &lds[BUF][12288 + wave * 1024]);               \
  }

// wait: stage(T) landed (NSTR newest loads may stay in flight), all our
// ds_reads of the buffer about to be overwritten done, barrier, then issue
// stage(T+3).
#define PHASE(T, NSTR)                                                         \
  {                                                                            \
    asm volatile("s_waitcnt vmcnt(" NSTR ") lgkmcnt(0)" ::: "memory");         \
    __builtin_amdgcn_sched_barrier(0);                                         \
    __builtin_amdgcn_s_barrier();                                              \
    if ((T) + 3 < 16) STAGE((T) + 3, ((T) + 3) & 3);                           \
  }

// ACC[0..3] = {g0s0, g0s1, g1s0, g1s1}; groups = 16-col halves of the panel
#define COMPUTE(ACC, BUF)                                                      \
  {                                                                            \
    const bf16x8* Bt = reinterpret_cast<const bf16x8*>(lds[BUF]);              \
    ACC[0] = (f32x4){0,0,0,0}; ACC[1] = (f32x4){0,0,0,0};                      \
    ACC[2] = (f32x4){0,0,0,0}; ACC[3] = (f32x4){0,0,0,0};                      \
    __builtin_amdgcn_s_setprio(1);                                             \
    _Pragma("unroll")                                                          \
    for (int kc = 0; kc < 8; ++kc) {                                           \
      bf16x8 b0 = Bt[kc * 64 + lane];                                          \
      bf16x8 b1 = Bt[512 + kc * 64 + lane];                                    \
      ACC[0] = __builtin_amdgcn_mfma_f32_16x16x32_bf16(a[0][kc], b0, ACC[0], 0, 0, 0); \
      ACC[1] = __builtin_amdgcn_mfma_f32_16x16x32_bf16(a[1][kc], b0, ACC[1], 0, 0, 0); \
      ACC[2] = __builtin_amdgcn_mfma_f32_16x16x32_bf16(a[0][kc], b1, ACC[2], 0, 0, 0); \
      ACC[3] = __builtin_amdgcn_mfma_f32_16x16x32_bf16(a[1][kc], b1, ACC[3], 0, 0, 0); \
    }                                                                          \
    __builtin_amdgcn_s_setprio(0);                                             \
  }

#define EPILOGUE(ACC, T)                                                       \
  {                                                                            \
    const int colbase = colstart + (T) * 32;                                   \
    if (colbase + 32 > rowbase && colbase < rowbase + 32) {                    \
      _Pragma("unroll")                                                        \
      for (int g = 0; g < 2; ++g) {                                            \
        const int bc = colbase + g * 16 + l15;                                 \
        const float w1 = wlab[(T) * 32 + g * 16 + l15];                        \
        _Pragma("unroll")                                                      \
        for (int s = 0; s < 2; ++s)                                            \
          _Pragma("unroll")                                                    \
          for (int r = 0; r < 4; ++r) {                                        \
            const int rr = rowbase + s * 16 + quad * 4 + r;                    \
            float e = (rr == bc) ? 0.0f : fast_exp2(ACC[g * 2 + s][r]);        \
            sall[s][r] += e; sp1[s][r] = fmaf(e, w1, sp1[s][r]);               \
          }                                                                    \
      }                                                                        \
    } else {                                                                   \
      _Pragma("unroll")                                                        \
      for (int g = 0; g < 2; ++g) {                                            \
        const float w1 = wlab[(T) * 32 + g * 16 + l15];                        \
        _Pragma("unroll")                                                      \
        for (int s = 0; s < 2; ++s)                                            \
          _Pragma("unroll")                                                    \
          for (int r = 0; r < 4; ++r) {                                        \
            float e = fast_exp2(ACC[g * 2 + s][r]);                            \
            sall[s][r] += e; sp1[s][r] = fmaf(e, w1, sp1[s][r]);               \
          }                                                                    \
      }                                                                        \
    }                                                                          \
  }

__global__ __launch_bounds__(256, 2) void gram_kernel(
    const __hip_bfloat16* __restrict__ fnf, const int* __restrict__ labels,
    float* __restrict__ S_all, float* __restrict__ S_1)
{
    __shared__ __align__(16) char lds[4][16384];
    __shared__ float wlab[512];

    const int tid  = threadIdx.x;
    const int lane = tid & 63;
    const int wave = tid >> 6;
    const int l15  = lane & 15;
    const int quad = lane >> 4;

    const int cs = blockIdx.x & 15;       // col split  (16 splits x 512 cols)
    const int rb = blockIdx.x >> 4;       // row block  (64 blocks x 128 rows)
    const int rowbase  = rb * 128 + wave * 32;
    const int colstart = cs * 512;

    const bf16x8* __restrict__ F = reinterpret_cast<const bf16x8*>(fnf);

    // A fragments: 2 sub-tiles x 8 k-chunks = 32 rows/wave, coalesced loads
    bf16x8 a[2][8];
    #pragma unroll
    for (int s = 0; s < 2; ++s)
        #pragma unroll
        for (int kc = 0; kc < 8; ++kc)
            a[s][kc] = F[(size_t)((((rowbase >> 4) + s) * 8 + kc)) * 64 + lane];

    float sall[2][4], sp1[2][4];
    #pragma unroll
    for (int s = 0; s < 2; ++s)
        #pragma unroll
        for (int r = 0; r < 4; ++r) { sall[s][r] = 0.0f; sp1[s][r] = 0.0f; }

    // prologue: 3 stages (12 loads) in flight, label weights to LDS
    STAGE(0, 0);
    STAGE(1, 1);
    STAGE(2, 2);
    #pragma unroll
    for (int i = tid; i < 512; i += 256) wlab[i] = (float)labels[colstart + i];

    f32x4 accA[4], accB[4];

    // phase 0: stage 0 landed (8 newest loads may fly), issue stage 3
    asm volatile("s_waitcnt vmcnt(8) lgkmcnt(0)" ::: "memory");
    __builtin_amdgcn_sched_barrier(0);
    __builtin_amdgcn_s_barrier();
    STAGE(3, 3);
    COMPUTE(accA, 0);

    PHASE(1, "8"); COMPUTE(accB, 1); EPILOGUE(accA, 0);

    int t = 2;
    #pragma unroll 1
    for (int it = 0; it < 6; ++it) {
        PHASE(t, "8"); COMPUTE(accA, t & 3); EPILOGUE(accB, t - 1); ++t;
        PHASE(t, "8"); COMPUTE(accB, t & 3); EPILOGUE(accA, t - 1); ++t;
    }
    // t == 14, 15
    PHASE(14, "4"); COMPUTE(accA, 2); EPILOGUE(accB, 13);
    PHASE(15, "0"); COMPUTE(accB, 3); EPILOGUE(accA, 14);
    EPILOGUE(accB, 15);

    // reduce over the 16 cols held across low lane bits, one atomic/row/block
    #pragma unroll
    for (int s = 0; s < 2; ++s)
        #pragma unroll
        for (int r = 0; r < 4; ++r) {
            float va = sall[s][r];
            float v1 = sp1[s][r];
            #pragma unroll
            for (int m = 1; m < 16; m <<= 1) {
                va += __shfl_xor(va, m);
                v1 += __shfl_xor(v1, m);
            }
            if (l15 == 0) {
                const int grow = rowbase + s * 16 + quad * 4 + r;
                atomicAdd(&S_all[grow], va);
                atomicAdd(&S_1[grow],  v1);
            }
        }
}

// ---------------------------------------------------------------------------
// finalize: fold 2048 sigma partials (redundantly per block, coalesced
// float4), then per-row losses + mean reduction into out[0].
// ---------------------------------------------------------------------------
__global__ __launch_bounds__(256) void finalize_kernel(
    const int* __restrict__ labels, const float* __restrict__ dist_sq,
    const float* __restrict__ S_all, const float* __restrict__ S_1,
    const float* __restrict__ stats_part, const float* __restrict__ rsigma,
    float* __restrict__ out)
{
    __shared__ float sh[3][4];
    const int lane = threadIdx.x & 63;
    const int wave = threadIdx.x >> 6;

    float c = 0.0f, s = 0.0f, q = 0.0f;
    const float4* sp = reinterpret_cast<const float4*>(stats_part);
    #pragma unroll
    for (int b = 0; b < 8; ++b) {
        const float4 v = sp[b * 256 + threadIdx.x];
        c += v.x; s += v.y; q += v.z;
    }
    #pragma unroll
    for (int m = 1; m < 64; m <<= 1) {
        c += __shfl_xor(c, m);
        s += __shfl_xor(s, m);
        q += __shfl_xor(q, m);
    }
    if (lane == 0) { sh[0][wave] = c; sh[1][wave] = s; sh[2][wave] = q; }
    __syncthreads();

    const float n0   = sh[0][0] + sh[0][1] + sh[0][2] + sh[0][3];
    const float ssx  = sh[1][0] + sh[1][1] + sh[1][2] + sh[1][3];
    const float snsq = sh[2][0] + sh[2][1] + sh[2][2] + sh[2][3];

    const float n_el = n0 * (float)DD;
    const float mean = ssx / n_el;
    const float var  = (snsq - n_el * mean * mean) / (n_el - 1.0f);
    const float sigma_new  = 0.9f * rsigma[0] + 0.1f * sqrtf(var);
    const float m_adaptive = 0.5f + 0.3f * sigma_new + 0.3f * (1.0f - 224.0f / 900.0f);

    const int i = blockIdx.x * 256 + threadIdx.x;
    const int l = labels[i];
    const float dsq = dist_sq[i];

    const float r_center = (l == 0) ? dsq : 0.0f;
    const float r_margin = (l == 1) ? fmaxf(m_adaptive - sqrtf(dsq), 0.0f) : 0.0f;

    const float sallv = S_all[i];
    const float s1v   = S_1[i];
    const float s0v   = sallv - s1v;
    const float pos = (l == 0) ? s0v : s1v;
    const float neg = (l == 0) ? s1v : s0v;

    const float n1 = (float)BB - n0;
    const float cnt_same = ((l == 0) ? n0 : n1) - 1.0f;
    const float cnt_diff = (l == 0) ? n1 : n0;

    float r_con = 0.0f;
    if (cnt_same > 0.0f && cnt_diff > 0.0f)
        r_con = logf(pos + neg + 1e-8f) - logf(pos);

    float tot = (r_center + r_margin + 0.5f * r_con) * (1.0f / (float)BB);

    #pragma unroll
    for (int m = 1; m < 64; m <<= 1) tot += __shfl_xor(tot, m);
    if ((threadIdx.x & 63) == 0) atomicAdd(out, tot);
}

// ---------------------------------------------------------------------------
// launch
// ---------------------------------------------------------------------------
extern "C" void kernel_launch(void* const* d_in, const int* in_sizes, int n_in,
                              void* d_out, int out_size, void* d_ws, size_t ws_size,
                              hipStream_t stream) {
    const float* feat   = (const float*)d_in[0];
    const int*   labels = (const int*)d_in[1];
    const float* center = (const float*)d_in[2];
    const float* rsigma = (const float*)d_in[3];
    float* out = (float*)d_out;

    char* ws = (char*)d_ws;
    __hip_bfloat16* fnf = (__hip_bfloat16*)ws;                    // B*D bf16 = 4 MB, fragment order
    float* dist_sq   = (float*)(ws + (size_t)BB * DD * 2);        // B floats
    float* S_all     = dist_sq + BB;                              // B floats
    float* S_1       = S_all + BB;                                // B floats
    float* stats_part= S_1 + BB;                                  // 2048*4 floats

    prep_kernel<<<dim3(BB / 4), dim3(256), 0, stream>>>(feat, labels, center, fnf,
                                                        dist_sq, stats_part, S_all, out);
    gram_kernel<<<dim3(64 * 16), dim3(256), 0, stream>>>(fnf, labels, S_all, S_1);
    finalize_kernel<<<dim3(BB / 256), dim3(256), 0, stream>>>(labels, dist_sq, S_all, S_1,
                                                              stats_part, rsigma, out);
}

// Round 6
// 109.242 us; speedup vs baseline: 1.0971x; 1.0033x over previous
//
#include <hip/hip_runtime.h>
#include <hip/hip_bf16.h>

#define BB 8192
#define DD 256
#define ZN (2 * BB)   // floats to zero: S_all, S_1

typedef float f32x4 __attribute__((ext_vector_type(4)));
typedef __bf16 bf16x8 __attribute__((ext_vector_type(8)));

// sqrt(log2(e)/0.07): fn rows pre-scaled so MFMA acc = sim * log2(e)/T directly
#define FSCALE 4.53981600f

// raw v_exp_f32: args here are |x| <= ~21, no range fixup needed
__device__ __forceinline__ float fast_exp2(float x) {
    float r;
    asm("v_exp_f32 %0, %1" : "=v"(r) : "v"(x));
    return r;
}

// ---------------------------------------------------------------------------
// prep: one wave per row. dist_sq vs center, sigma partials (block-reduced,
// race-free into stats_part[block]), writes the normalized+scaled row in MFMA
// FRAGMENT ORDER. Also zeroes S_all/S_1/out.
// ---------------------------------------------------------------------------
__global__ __launch_bounds__(256) void prep_kernel(
    const float* __restrict__ feat, const int* __restrict__ labels,
    const float* __restrict__ center, __hip_bfloat16* __restrict__ fnf,
    float* __restrict__ dist_sq, float* __restrict__ stats_part,
    float* __restrict__ zacc, float* __restrict__ out)
{
    __shared__ float sh[3][4];
    const int gid = blockIdx.x * 256 + threadIdx.x;
    if (gid < ZN) zacc[gid] = 0.0f;
    if (gid == 0) out[0] = 0.0f;

    const int wave = threadIdx.x >> 6;
    const int lane = threadIdx.x & 63;
    const int row  = blockIdx.x * 4 + wave;

    const float4* frow = reinterpret_cast<const float4*>(feat + (size_t)row * DD);
    const float4* crow = reinterpret_cast<const float4*>(center);
    float4 x = frow[lane];
    float4 c = crow[lane];

    float d0 = x.x - c.x, d1 = x.y - c.y, d2 = x.z - c.z, d3 = x.w - c.w;
    float dsq = d0*d0 + d1*d1 + d2*d2 + d3*d3;
    float nsq = x.x*x.x + x.y*x.y + x.z*x.z + x.w*x.w;
    float sx  = x.x + x.y + x.z + x.w;

    #pragma unroll
    for (int m = 1; m < 64; m <<= 1) {
        dsq += __shfl_xor(dsq, m);
        nsq += __shfl_xor(nsq, m);
        sx  += __shfl_xor(sx,  m);
    }

    float rn = FSCALE / fmaxf(sqrtf(nsq), 1e-12f);

    ushort4 u;
    u.x = __builtin_bit_cast(unsigned short, __float2bfloat16(x.x * rn));
    u.y = __builtin_bit_cast(unsigned short, __float2bfloat16(x.y * rn));
    u.z = __builtin_bit_cast(unsigned short, __float2bfloat16(x.z * rn));
    u.w = __builtin_bit_cast(unsigned short, __float2bfloat16(x.w * rn));

    // lane holds elems e=4*lane..+3: kc=lane/8, quad=(lane%8)/2, half=lane&1
    const int g    = row >> 4;
    const int l15r = row & 15;
    const int kc   = lane >> 3;
    const int qd   = (lane & 7) >> 1;
    const int half = lane & 1;
    const size_t cell = (size_t)((g * 8 + kc) * 64 + qd * 16 + l15r);
    reinterpret_cast<ushort4*>(fnf)[cell * 2 + half] = u;

    if (lane == 0) {
        const float m0 = (labels[row] == 0) ? 1.0f : 0.0f;
        dist_sq[row] = dsq;
        sh[0][wave] = m0;
        sh[1][wave] = sx  * m0;
        sh[2][wave] = nsq * m0;
    }
    __syncthreads();
    if (threadIdx.x == 0) {
        float* sp = stats_part + (size_t)blockIdx.x * 4;
        sp[0] = sh[0][0] + sh[0][1] + sh[0][2] + sh[0][3];
        sp[1] = sh[1][0] + sh[1][1] + sh[1][2] + sh[1][3];
        sp[2] = sh[2][0] + sh[2][1] + sh[2][2] + sh[2][3];
        sp[3] = 0.0f;
    }
}

// ---------------------------------------------------------------------------
// gram v7: de-phased, barrier-free, LDS-free B path.
// Evidence (v3==v4==v6==~45us, invariant to phases/occupancy/LDS traffic):
// the barrier-phase-locked structure serializes the pipes within each phase.
// v7 removes the structure: fnf is L2-resident (4MB) and already in fragment
// order, so B fragments load DIRECTLY global->VGPR (coalesced dwordx4).
// Each wave = independent pipeline, fixed-role 2-deep register prefetch:
//   bvP = lo-half (kc0-3) of next tile, loaded after it's consumed;
//   bvC = hi-half (kc4-7) of current tile, loaded at tile start.
// 64 rows/wave (a[4][8]) halves redundant B traffic; 512 blocks = ALL
// resident (2/CU); XCD swizzle keeps each XCD's 2 col-splits L2-local.
// One barrier total (wlab init). No LDS for B, no vmcnt choreography.
// ---------------------------------------------------------------------------
#define LOAD4(BV, T, KB)                                                       \
  {                                                                            \
    _Pragma("unroll")                                                          \
    for (int k = 0; k < 4; ++k)                                                \
      BV[k] = F[((size_t)(cpanel + (T)) * 8 + (KB) + k) * 64 + lane];          \
  }

#define MFMA16(BV, KB)                                                         \
  {                                                                            \
    _Pragma("unroll")                                                          \
    for (int k = 0; k < 4; ++k) {                                              \
      acc[0] = __builtin_amdgcn_mfma_f32_16x16x32_bf16(a[0][(KB) + k], BV[k], acc[0], 0, 0, 0); \
      acc[1] = __builtin_amdgcn_mfma_f32_16x16x32_bf16(a[1][(KB) + k], BV[k], acc[1], 0, 0, 0); \
      acc[2] = __builtin_amdgcn_mfma_f32_16x16x32_bf16(a[2][(KB) + k], BV[k], acc[2], 0, 0, 0); \
      acc[3] = __builtin_amdgcn_mfma_f32_16x16x32_bf16(a[3][(KB) + k], BV[k], acc[3], 0, 0, 0); \
    }                                                                          \
  }

#define EPILOGUE(T)                                                            \
  {                                                                            \
    const int colbase = colstart + (T) * 16;                                   \
    const int bcol = colbase + l15;                                            \
    const float w1 = wlab[(T) * 16 + l15];                                     \
    if (colbase + 16 > rowbase && colbase < rowbase + 64) {                    \
      _Pragma("unroll")                                                        \
      for (int s = 0; s < 4; ++s)                                              \
        _Pragma("unroll")                                                      \
        for (int r = 0; r < 4; ++r) {                                          \
          const int rr = rowbase + s * 16 + quad * 4 + r;                      \
          float e = (rr == bcol) ? 0.0f : fast_exp2(acc[s][r]);                \
          sall[s][r] += e; sp1[s][r] = fmaf(e, w1, sp1[s][r]);                 \
        }                                                                      \
    } else {                                                                   \
      _Pragma("unroll")                                                        \
      for (int s = 0; s < 4; ++s)                                              \
        _Pragma("unroll")                                                      \
        for (int r = 0; r < 4; ++r) {                                          \
          float e = fast_exp2(acc[s][r]);                                      \
          sall[s][r] += e; sp1[s][r] = fmaf(e, w1, sp1[s][r]);                 \
        }                                                                      \
    }                                                                          \
  }

__global__ __launch_bounds__(256, 2) void gram_kernel(
    const __hip_bfloat16* __restrict__ fnf, const int* __restrict__ labels,
    float* __restrict__ S_all, float* __restrict__ S_1)
{
    __shared__ float wlab[512];

    const int tid  = threadIdx.x;
    const int lane = tid & 63;
    const int wave = tid >> 6;
    const int l15  = lane & 15;
    const int quad = lane >> 4;

    // XCD-aware swizzle: 512 blocks; xcd = bid%8 hosts col-splits {2x, 2x+1}
    const int bid = blockIdx.x;
    const int xcd = bid & 7;
    const int j   = bid >> 3;            // 0..63
    const int cs  = xcd * 2 + (j & 1);   // col split 0..15
    const int rb  = j >> 1;              // row block 0..31

    const int rowbase  = rb * 256 + wave * 64;
    const int colstart = cs * 512;
    const int cpanel   = colstart >> 4;  // first 16-col cell group

    const bf16x8* __restrict__ F = reinterpret_cast<const bf16x8*>(fnf);

    // A fragments: 4 sub-tiles x 8 k-chunks = 64 rows/wave, coalesced loads
    bf16x8 a[4][8];
    #pragma unroll
    for (int s = 0; s < 4; ++s)
        #pragma unroll
        for (int kc = 0; kc < 8; ++kc)
            a[s][kc] = F[(size_t)((((rowbase >> 4) + s) * 8 + kc)) * 64 + lane];

    float sall[4][4], sp1[4][4];
    #pragma unroll
    for (int s = 0; s < 4; ++s)
        #pragma unroll
        for (int r = 0; r < 4; ++r) { sall[s][r] = 0.0f; sp1[s][r] = 0.0f; }

    #pragma unroll
    for (int i = tid; i < 512; i += 256) wlab[i] = (float)labels[colstart + i];
    __syncthreads();        // the ONLY barrier; waves de-phase after this

    f32x4 acc[4];
    bf16x8 bvP[4], bvC[4];  // fixed roles: bvP = lo(next), bvC = hi(current)

    LOAD4(bvP, 0, 0);       // prefetch tile 0 lo-half

    #pragma unroll 1
    for (int t = 0; t < 31; ++t) {
        LOAD4(bvC, t, 4);           // current hi-half, in flight under MFMA-lo
        acc[0] = (f32x4){0,0,0,0}; acc[1] = (f32x4){0,0,0,0};
        acc[2] = (f32x4){0,0,0,0}; acc[3] = (f32x4){0,0,0,0};
        MFMA16(bvP, 0);             // consume lo (prefetched last tile)
        LOAD4(bvP, t + 1, 0);       // prefetch next lo (WAR: after consume)
        MFMA16(bvC, 4);             // vmcnt wait for bvC folds under MFMA-lo
        EPILOGUE(t);
    }
    // t == 31
    LOAD4(bvC, 31, 4);
    acc[0] = (f32x4){0,0,0,0}; acc[1] = (f32x4){0,0,0,0};
    acc[2] = (f32x4){0,0,0,0}; acc[3] = (f32x4){0,0,0,0};
    MFMA16(bvP, 0);
    MFMA16(bvC, 4);
    EPILOGUE(31);

    // reduce over the 16 cols held across low lane bits, one atomic/row/block
    #pragma unroll
    for (int s = 0; s < 4; ++s)
        #pragma unroll
        for (int r = 0; r < 4; ++r) {
            float va = sall[s][r];
            float v1 = sp1[s][r];
            #pragma unroll
            for (int m = 1; m < 16; m <<= 1) {
                va += __shfl_xor(va, m);
                v1 += __shfl_xor(v1, m);
            }
            if (l15 == 0) {
                const int grow = rowbase + s * 16 + quad * 4 + r;
                atomicAdd(&S_all[grow], va);
                atomicAdd(&S_1[grow],  v1);
            }
        }
}

// ---------------------------------------------------------------------------
// finalize: fold 2048 sigma partials (redundantly per block, coalesced
// float4), then per-row losses + mean reduction into out[0].
// ---------------------------------------------------------------------------
__global__ __launch_bounds__(256) void finalize_kernel(
    const int* __restrict__ labels, const float* __restrict__ dist_sq,
    const float* __restrict__ S_all, const float* __restrict__ S_1,
    const float* __restrict__ stats_part, const float* __restrict__ rsigma,
    float* __restrict__ out)
{
    __shared__ float sh[3][4];
    const int lane = threadIdx.x & 63;
    const int wave = threadIdx.x >> 6;

    float c = 0.0f, s = 0.0f, q = 0.0f;
    const float4* sp = reinterpret_cast<const float4*>(stats_part);
    #pragma unroll
    for (int b = 0; b < 8; ++b) {
        const float4 v = sp[b * 256 + threadIdx.x];
        c += v.x; s += v.y; q += v.z;
    }
    #pragma unroll
    for (int m = 1; m < 64; m <<= 1) {
        c += __shfl_xor(c, m);
        s += __shfl_xor(s, m);
        q += __shfl_xor(q, m);
    }
    if (lane == 0) { sh[0][wave] = c; sh[1][wave] = s; sh[2][wave] = q; }
    __syncthreads();

    const float n0   = sh[0][0] + sh[0][1] + sh[0][2] + sh[0][3];
    const float ssx  = sh[1][0] + sh[1][1] + sh[1][2] + sh[1][3];
    const float snsq = sh[2][0] + sh[2][1] + sh[2][2] + sh[2][3];

    const float n_el = n0 * (float)DD;
    const float mean = ssx / n_el;
    const float var  = (snsq - n_el * mean * mean) / (n_el - 1.0f);
    const float sigma_new  = 0.9f * rsigma[0] + 0.1f * sqrtf(var);
    const float m_adaptive = 0.5f + 0.3f * sigma_new + 0.3f * (1.0f - 224.0f / 900.0f);

    const int i = blockIdx.x * 256 + threadIdx.x;
    const int l = labels[i];
    const float dsq = dist_sq[i];

    const float r_center = (l == 0) ? dsq : 0.0f;
    const float r_margin = (l == 1) ? fmaxf(m_adaptive - sqrtf(dsq), 0.0f) : 0.0f;

    const float sallv = S_all[i];
    const float s1v   = S_1[i];
    const float s0v   = sallv - s1v;
    const float pos = (l == 0) ? s0v : s1v;
    const float neg = (l == 0) ? s1v : s0v;

    const float n1 = (float)BB - n0;
    const float cnt_same = ((l == 0) ? n0 : n1) - 1.0f;
    const float cnt_diff = (l == 0) ? n1 : n0;

    float r_con = 0.0f;
    if (cnt_same > 0.0f && cnt_diff > 0.0f)
        r_con = logf(pos + neg + 1e-8f) - logf(pos);

    float tot = (r_center + r_margin + 0.5f * r_con) * (1.0f / (float)BB);

    #pragma unroll
    for (int m = 1; m < 64; m <<= 1) tot += __shfl_xor(tot, m);
    if ((threadIdx.x & 63) == 0) atomicAdd(out, tot);
}

// ---------------------------------------------------------------------------
// launch
// ---------------------------------------------------------------------------
extern "C" void kernel_launch(void* const* d_in, const int* in_sizes, int n_in,
                              void* d_out, int out_size, void* d_ws, size_t ws_size,
                              hipStream_t stream) {
    const float* feat   = (const float*)d_in[0];
    const int*   labels = (const int*)d_in[1];
    const float* center = (const float*)d_in[2];
    const float* rsigma = (const float*)d_in[3];
    float* out = (float*)d_out;

    char* ws = (char*)d_ws;
    __hip_bfloat16* fnf = (__hip_bfloat16*)ws;                    // B*D bf16 = 4 MB, fragment order
    float* dist_sq   = (float*)(ws + (size_t)BB * DD * 2);        // B floats
    float* S_all     = dist_sq + BB;                              // B floats
    float* S_1       = S_all + BB;                                // B floats
    float* stats_part= S_1 + BB;                                  // 2048*4 floats

    prep_kernel<<<dim3(BB / 4), dim3(256), 0, stream>>>(feat, labels, center, fnf,
                                                        dist_sq, stats_part, S_all, out);
    gram_kernel<<<dim3(512), dim3(256), 0, stream>>>(fnf, labels, S_all, S_1);
    finalize_kernel<<<dim3(BB / 256), dim3(256), 0, stream>>>(labels, dist_sq, S_all, S_1,
                                                              stats_part, rsigma, out);
}